// Round 3
// 387.560 us; speedup vs baseline: 1.5107x; 1.5107x over previous
//
#include <hip/hip_runtime.h>
#include <cstddef>
#include <cstdint>

#define N_DIM 64
#define C_IN 64
#define C_OUT 128
#define T_DIM 300
#define V_DIM 25
#define TVTOT (T_DIM * V_DIM)                 // 7500
#define TILE 64                               // tv columns per block
#define NTILE ((TVTOT + TILE - 1) / TILE)     // 118 (last tile: 12 valid cols)
#define KTOT 192                              // 3 * C_IN (k folded into K)
#define NKS (KTOT / 32)                       // 6 MFMA k-steps
#define ROWB 384                              // LDS row stride bytes (192 bf16)
#define WFRAG_BYTES (8 * NKS * 64 * 8 * 2)    // 49152

typedef unsigned int uint32;
typedef unsigned short ushort16;
typedef float f32x4 __attribute__((ext_vector_type(4)));
typedef short bf16x8 __attribute__((ext_vector_type(8)));
typedef uint32 u32x4 __attribute__((ext_vector_type(4)));

__device__ __forceinline__ ushort16 f2bf(float f) {
  uint32 u = __float_as_uint(f);
  u = (u + 0x7FFFu + ((u >> 16) & 1u)) >> 16;   // RNE
  return (ushort16)u;
}
__device__ __forceinline__ uint32 pack2(float a, float b) {
  return (uint32)f2bf(a) | ((uint32)f2bf(b) << 16);
}

// ---------------- prep ------------------------------------------------------
// sS4[v*4 + k] = sum_w A[k][index[v]][w]   (k=0..2; [3] zeroed)
// Wfrag[m][ks][lane][j] = bf16(W[(k*C_OUT + c)*C_IN + i]) in exact A-fragment
//   order for mfma_f32_16x16x32_bf16: c = 16m + (lane&15), kk = 32ks + 8*(lane>>4) + j
__global__ __launch_bounds__(384)
void sgc_prep(const float* __restrict__ A, const float* __restrict__ W,
              const int* __restrict__ index,
              ushort16* __restrict__ Wfrag, float* __restrict__ sS4) {
  const int m = blockIdx.x;        // 0..7 (M-fragment)
  const int tid = threadIdx.x;     // 0..383

  if (m == 0 && tid < 3 * V_DIM) {
    const int k = tid / V_DIM;
    const int v = tid - k * V_DIM;
    const int idx = index[v];
    float s = 0.f;
    #pragma unroll
    for (int w = 0; w < V_DIM; ++w) s += A[(k * V_DIM + idx) * V_DIM + w];
    sS4[v * 4 + k] = s;
    if (k == 0) sS4[v * 4 + 3] = 0.f;
  }

  const int ks = tid >> 6;                     // 0..5
  const int lane = tid & 63;
  const int c = (m << 4) + (lane & 15);
  const int kk0 = (ks << 5) + ((lane >> 4) << 3);  // octet start, stays in one k
  const int k = kk0 >> 6;
  const int i0 = kk0 & 63;
  const float* wrow = W + (size_t)(k * C_OUT + c) * C_IN + i0;
  u32x4 w4;
  #pragma unroll
  for (int p = 0; p < 4; ++p)
    w4[p] = pack2(wrow[2 * p], wrow[2 * p + 1]);
  *(u32x4*)((ushort16*)Wfrag + (((m * NKS + ks) * 64 + lane) << 3)) = w4;
}

// ---------------- main ------------------------------------------------------
// out[c, tv] = sum_kk Wcat[c][kk] * xcat[kk][tv] + sum_k s_k[v]*bias[k*128+c]
//   xcat[k*64+i][tv] = s_k[v(tv)] * x[i][tv]
__global__ __launch_bounds__(256)
void sgc_main(const float* __restrict__ x, const ushort16* __restrict__ Wfrag,
              const float* __restrict__ sS4, const float* __restrict__ bias,
              float* __restrict__ out) {
  // [tv=64][kk=192] bf16, 16B slots XOR-swizzled by (tv&7) -> conflict-free b128 r/w
  __shared__ __align__(16) ushort16 xs[TILE * (ROWB / 2)];   // 24576 B

  const int tid = threadIdx.x;
  const int wv = tid >> 6;          // wave 0..3
  const int lane = tid & 63;
  const int tile = blockIdx.x;
  const int n = blockIdx.y;
  const int tv0 = tile * TILE;

  // ---- A fragments: wave wv owns M-frags {2wv, 2wv+1}; coalesced b128 from L2
  bf16x8 afr[2][NKS];
  #pragma unroll
  for (int m2 = 0; m2 < 2; ++m2)
    #pragma unroll
    for (int ks = 0; ks < NKS; ++ks)
      afr[m2][ks] = *(const bf16x8*)((const ushort16*)Wfrag +
                        ((((2 * wv + m2) * NKS + ks) * 64 + lane) << 3));

  // ---- stage x: thread owns one tv column, 16 consecutive i (coalesced dwords)
  const int tvg = tv0 + lane;
  const bool tvok = tvg < TVTOT;
  const int vstage = tvok ? (tvg % V_DIM) : 0;
  const f32x4 sv = *(const f32x4*)(sS4 + 4 * vstage);
  float xv[16];
  {
    const float* xp = x + ((size_t)n * C_IN + wv * 16) * TVTOT + tvg;
    if (tvok) {
      #pragma unroll
      for (int j = 0; j < 16; ++j) xv[j] = xp[j * TVTOT];
    } else {
      #pragma unroll
      for (int j = 0; j < 16; ++j) xv[j] = 0.f;
    }
  }
  #pragma unroll
  for (int k = 0; k < 3; ++k) {
    const float sk = sv[k];
    u32x4 w0, w1;
    #pragma unroll
    for (int p = 0; p < 4; ++p) {
      w0[p] = pack2(xv[2 * p] * sk, xv[2 * p + 1] * sk);
      w1[p] = pack2(xv[8 + 2 * p] * sk, xv[9 + 2 * p] * sk);
    }
    const int sb = k * 8 + 2 * wv;              // 16B-slot base: (k*64 + wv*16)/8
    char* rowp = (char*)xs + lane * ROWB;
    *(u32x4*)(rowp + ((sb ^ (lane & 7)) << 4)) = w0;
    *(u32x4*)(rowp + (((sb + 1) ^ (lane & 7)) << 4)) = w1;
  }
  __syncthreads();

  // ---- MFMA: 2 M-frags x 4 N-frags x 6 k-steps per wave
  f32x4 acc[2][4];
  #pragma unroll
  for (int m2 = 0; m2 < 2; ++m2)
    #pragma unroll
    for (int f = 0; f < 4; ++f) acc[m2][f] = (f32x4){0.f, 0.f, 0.f, 0.f};

  #pragma unroll
  for (int ks = 0; ks < NKS; ++ks) {
    bf16x8 bfr[4];
    #pragma unroll
    for (int f = 0; f < 4; ++f) {
      const int col = 16 * f + (lane & 15);
      const int sl = (4 * ks + (lane >> 4)) ^ (lane & 7);
      bfr[f] = *(const bf16x8*)((const char*)xs + col * ROWB + (sl << 4));
    }
    #pragma unroll
    for (int m2 = 0; m2 < 2; ++m2)
      #pragma unroll
      for (int f = 0; f < 4; ++f)
        acc[m2][f] = __builtin_amdgcn_mfma_f32_16x16x32_bf16(
            afr[m2][ks], bfr[f], acc[m2][f], 0, 0, 0);
  }

  // ---- epilogue: rows c = 32wv + 16m2 + 4*(lane>>4) + q ; col = tv0 + 16f + (lane&15)
  const int rg = (lane >> 4) << 2;
  f32x4 bfr3[2][3];
  #pragma unroll
  for (int m2 = 0; m2 < 2; ++m2) {
    const int c0 = 32 * wv + 16 * m2 + rg;
    #pragma unroll
    for (int k = 0; k < 3; ++k)
      bfr3[m2][k] = *(const f32x4*)(bias + k * C_OUT + c0);
  }
  float* outn = out + (size_t)n * C_OUT * TVTOT;
  #pragma unroll
  for (int f = 0; f < 4; ++f) {
    const int tvc = tv0 + 16 * f + (lane & 15);
    if (tvc < TVTOT) {
      const int v = tvc % V_DIM;
      const f32x4 s2 = *(const f32x4*)(sS4 + 4 * v);
      #pragma unroll
      for (int m2 = 0; m2 < 2; ++m2) {
        const int c0 = 32 * wv + 16 * m2 + rg;
        const f32x4 badd =
            s2[0] * bfr3[m2][0] + s2[1] * bfr3[m2][1] + s2[2] * bfr3[m2][2];
        const f32x4 r = acc[m2][f] + badd;
        #pragma unroll
        for (int q = 0; q < 4; ++q)
          outn[(size_t)(c0 + q) * TVTOT + tvc] = r[q];
      }
    }
  }
}

extern "C" void kernel_launch(void* const* d_in, const int* in_sizes, int n_in,
                              void* d_out, int out_size, void* d_ws, size_t ws_size,
                              hipStream_t stream) {
  const float* x      = (const float*)d_in[0];
  const float* A      = (const float*)d_in[1];
  const float* weight = (const float*)d_in[2];
  const float* bias   = (const float*)d_in[3];
  const int*   index  = (const int*)d_in[4];
  float* out = (float*)d_out;

  ushort16* Wfrag = (ushort16*)d_ws;                           // 49152 B
  float* sS4 = (float*)((char*)d_ws + WFRAG_BYTES);            // 25*4 floats

  sgc_prep<<<dim3(8), dim3(384), 0, stream>>>(A, weight, index, Wfrag, sS4);
  sgc_main<<<dim3(NTILE, N_DIM), dim3(256), 0, stream>>>(x, Wfrag, sS4, bias, out);
}